// Round 1
// baseline (538.075 us; speedup 1.0000x reference)
//
#include <hip/hip_runtime.h>
#include <math.h>

// ---------------------------------------------------------------------------
// RGAT (2-layer graph attention) on MI355X.
// N=50000 nodes, E=800000 edges, IN=64, HID=64, OUT=8.
// Strategy: fp32 throughout.
//   gemm1 (wave/row, W in LDS, fused e_src/e_dst reductions)
//   edge pass A: logit + atomicMax (monotone-uint float encoding, 0 == -inf)
//   edge pass B: exp(logit - max) + atomicAdd denom
//   scatter: wave/edge, lane==channel (C=64) ; 8 edges/wave for C=8
//   relu+bias, layer 2, per-node log_softmax.
// ---------------------------------------------------------------------------

__device__ __forceinline__ unsigned fenc(float f) {
    unsigned u = __float_as_uint(f);
    return (u & 0x80000000u) ? ~u : (u | 0x80000000u);
}
__device__ __forceinline__ float fdec(unsigned e) {
    return __uint_as_float((e & 0x80000000u) ? (e & 0x7FFFFFFFu) : ~e);
}

// h = x @ W (64x64), es = h@a_src, ed = h@a_dst.  One wave per row.
__global__ void __launch_bounds__(256) gemm1_kernel(
    const float* __restrict__ x, const float* __restrict__ W,
    const float* __restrict__ a_src, const float* __restrict__ a_dst,
    float* __restrict__ h, float* __restrict__ es, float* __restrict__ ed, int N)
{
    __shared__ float Wl[64 * 64];
    __shared__ float asl[64], adl[64];
    for (int i = threadIdx.x; i < 64 * 64; i += 256) Wl[i] = W[i];
    if (threadIdx.x < 64) {
        asl[threadIdx.x] = a_src[threadIdx.x];
        adl[threadIdx.x] = a_dst[threadIdx.x];
    }
    __syncthreads();
    const int lane = threadIdx.x & 63;
    const int wid  = threadIdx.x >> 6;
    for (int row = blockIdx.x * 4 + wid; row < N; row += gridDim.x * 4) {
        float xv = x[(size_t)row * 64 + lane];
        float acc = 0.f;
        #pragma unroll
        for (int k = 0; k < 64; ++k) {
            float xk = __shfl(xv, k);
            acc += xk * Wl[k * 64 + lane];
        }
        h[(size_t)row * 64 + lane] = acc;
        float ps = acc * asl[lane];
        float pd = acc * adl[lane];
        #pragma unroll
        for (int off = 32; off > 0; off >>= 1) {
            ps += __shfl_down(ps, off);
            pd += __shfl_down(pd, off);
        }
        if (lane == 0) { es[row] = ps; ed[row] = pd; }
    }
}

// h2 = hid @ W2 (64x8), e2s/e2d per row.  8 rows per wave (lane = r*8+c).
__global__ void __launch_bounds__(256) gemm2_kernel(
    const float* __restrict__ hid, const float* __restrict__ W,
    const float* __restrict__ a_src, const float* __restrict__ a_dst,
    float* __restrict__ h2, float* __restrict__ es, float* __restrict__ ed, int N)
{
    __shared__ float Wl[64 * 8];
    __shared__ float asl[8], adl[8];
    for (int i = threadIdx.x; i < 64 * 8; i += 256) Wl[i] = W[i];
    if (threadIdx.x < 8) {
        asl[threadIdx.x] = a_src[threadIdx.x];
        adl[threadIdx.x] = a_dst[threadIdx.x];
    }
    __syncthreads();
    const int lane = threadIdx.x & 63;
    const int wid  = threadIdx.x >> 6;
    const int r = lane >> 3, c = lane & 7;
    for (int base = (blockIdx.x * 4 + wid) * 8; base < N; base += gridDim.x * 32) {
        int row = base + r;
        float acc = 0.f;
        if (row < N) {
            #pragma unroll 8
            for (int k = 0; k < 64; ++k)
                acc += hid[(size_t)row * 64 + k] * Wl[k * 8 + c];
            h2[(size_t)row * 8 + c] = acc;
        }
        float ps = acc * asl[c];
        float pd = acc * adl[c];
        #pragma unroll
        for (int off = 4; off > 0; off >>= 1) {
            ps += __shfl_xor(ps, off);
            pd += __shfl_xor(pd, off);
        }
        if (row < N && c == 0) { es[row] = ps; ed[row] = pd; }
    }
}

// Pass A: logit[e] = leaky_relu(es[src]+ed[dst]); segment max into m (encoded).
__global__ void __launch_bounds__(256) edge_logit_max_kernel(
    const int* __restrict__ src, const int* __restrict__ dst,
    const float* __restrict__ es, const float* __restrict__ ed,
    float* __restrict__ logit, unsigned* __restrict__ m, int E)
{
    for (int e = blockIdx.x * 256 + threadIdx.x; e < E; e += gridDim.x * 256) {
        int s = src[e], d = dst[e];
        float z = es[s] + ed[d];
        float l = z > 0.f ? z : 0.2f * z;
        logit[e] = l;
        atomicMax(&m[d], fenc(l));
    }
}

// Pass B: logit -> exp(logit - m[dst]) in place; denom[dst] += exp.
__global__ void __launch_bounds__(256) edge_exp_denom_kernel(
    const int* __restrict__ dst, float* __restrict__ logit,
    const unsigned* __restrict__ m, float* __restrict__ denom, int E)
{
    for (int e = blockIdx.x * 256 + threadIdx.x; e < E; e += gridDim.x * 256) {
        int d = dst[e];
        float ex = expf(logit[e] - fdec(m[d]));
        logit[e] = ex;
        atomicAdd(&denom[d], ex);
    }
}

// Scatter C=64: one wave per edge, lane = channel.
__global__ void __launch_bounds__(256) scatter64_kernel(
    const int* __restrict__ src, const int* __restrict__ dst,
    const float* __restrict__ ex, const float* __restrict__ denom,
    const float* __restrict__ ev, const float* __restrict__ h,
    float* __restrict__ agg, int E)
{
    int e = blockIdx.x * 4 + (threadIdx.x >> 6);
    if (e >= E) return;
    int lane = threadIdx.x & 63;
    int s = src[e], d = dst[e];
    float coef = ex[e] / (denom[d] + 1e-16f) * ev[e];
    atomicAdd(&agg[(size_t)d * 64 + lane], coef * h[(size_t)s * 64 + lane]);
}

// Scatter C=8: 8 edges per wave, lane = eo*8 + c.
__global__ void __launch_bounds__(256) scatter8_kernel(
    const int* __restrict__ src, const int* __restrict__ dst,
    const float* __restrict__ ex, const float* __restrict__ denom,
    const float* __restrict__ ev, const float* __restrict__ h,
    float* __restrict__ agg, int E)
{
    int lane = threadIdx.x & 63;
    int eo = lane >> 3, c = lane & 7;
    int e = (blockIdx.x * 4 + (threadIdx.x >> 6)) * 8 + eo;
    if (e >= E) return;
    int s = src[e], d = dst[e];
    float coef = ex[e] / (denom[d] + 1e-16f) * ev[e];
    atomicAdd(&agg[(size_t)d * 8 + c], coef * h[(size_t)s * 8 + c]);
}

// hid = relu(agg + b[col]) in place (C=64).
__global__ void __launch_bounds__(256) relu_bias_kernel(
    float* __restrict__ a, const float* __restrict__ b, int total)
{
    int i = blockIdx.x * 256 + threadIdx.x;
    if (i < total) {
        float v = a[i] + b[i & 63];
        a[i] = v > 0.f ? v : 0.f;
    }
}

// out[n][:] = log_softmax(agg2[n][:] + b2), C=8; one thread per node.
__global__ void __launch_bounds__(256) logsoftmax_kernel(
    const float* __restrict__ agg, const float* __restrict__ b,
    float* __restrict__ out, int N)
{
    int n = blockIdx.x * 256 + threadIdx.x;
    if (n >= N) return;
    float v[8];
    float mx = -1e30f;
    #pragma unroll
    for (int c = 0; c < 8; ++c) {
        v[c] = agg[(size_t)n * 8 + c] + b[c];
        mx = fmaxf(mx, v[c]);
    }
    float s = 0.f;
    #pragma unroll
    for (int c = 0; c < 8; ++c) s += expf(v[c] - mx);
    float l = mx + logf(s);
    #pragma unroll
    for (int c = 0; c < 8; ++c) out[(size_t)n * 8 + c] = v[c] - l;
}

extern "C" void kernel_launch(void* const* d_in, const int* in_sizes, int n_in,
                              void* d_out, int out_size, void* d_ws, size_t ws_size,
                              hipStream_t stream)
{
    const float* x   = (const float*)d_in[0];
    const int*   ei  = (const int*)d_in[1];
    const float* ev  = (const float*)d_in[2];
    const float* W1  = (const float*)d_in[3];
    const float* a1s = (const float*)d_in[4];
    const float* a1d = (const float*)d_in[5];
    const float* b1  = (const float*)d_in[6];
    const float* W2  = (const float*)d_in[7];
    const float* a2s = (const float*)d_in[8];
    const float* a2d = (const float*)d_in[9];
    const float* b2  = (const float*)d_in[10];
    float* out = (float*)d_out;

    const int N = in_sizes[0] / 64;
    const int E = in_sizes[2];
    const int* srcp = ei;
    const int* dstp = ei + E;

    // Workspace layout (floats). Zero-init region first (single memset):
    //   agg1 N*64 | agg2 N*8 | m1 N | den1 N | m2 N | den2 N   <- zeroed
    //   h1 N*64 | h2 N*8 | e1s N | e1d N | e2s N | e2d N | logit E
    float* ws   = (float*)d_ws;
    float*    agg1 = ws;                          // N*64
    float*    agg2 = agg1 + (size_t)N * 64;       // N*8
    unsigned* m1   = (unsigned*)(agg2 + (size_t)N * 8); // N
    float*    den1 = (float*)(m1 + N);            // N
    unsigned* m2   = (unsigned*)(den1 + N);       // N
    float*    den2 = (float*)(m2 + N);            // N
    float*    h1   = den2 + N;                    // N*64
    float*    h2   = h1 + (size_t)N * 64;         // N*8
    float*    e1s  = h2 + (size_t)N * 8;          // N
    float*    e1d  = e1s + N;
    float*    e2s  = e1d + N;
    float*    e2d  = e2s + N;
    float*    lg   = e2d + N;                     // E

    size_t zero_bytes = (size_t)((char*)h1 - (char*)ws);
    hipMemsetAsync(d_ws, 0, zero_bytes, stream);  // agg/m/denom all zero (enc(0) < enc(any float))

    // ---- Layer 1 ----
    gemm1_kernel<<<2048, 256, 0, stream>>>(x, W1, a1s, a1d, h1, e1s, e1d, N);
    edge_logit_max_kernel<<<1024, 256, 0, stream>>>(srcp, dstp, e1s, e1d, lg, m1, E);
    edge_exp_denom_kernel<<<1024, 256, 0, stream>>>(dstp, lg, m1, den1, E);
    scatter64_kernel<<<(E + 3) / 4, 256, 0, stream>>>(srcp, dstp, lg, den1, ev, h1, agg1, E);
    relu_bias_kernel<<<(N * 64 + 255) / 256, 256, 0, stream>>>(agg1, b1, N * 64);

    // ---- Layer 2 ----
    gemm2_kernel<<<1024, 256, 0, stream>>>(agg1, W2, a2s, a2d, h2, e2s, e2d, N);
    edge_logit_max_kernel<<<1024, 256, 0, stream>>>(srcp, dstp, e2s, e2d, lg, m2, E);
    edge_exp_denom_kernel<<<1024, 256, 0, stream>>>(dstp, lg, m2, den2, E);
    scatter8_kernel<<<(E / 8 + 3) / 4, 256, 0, stream>>>(srcp, dstp, lg, den2, ev, h2, agg2, E);
    logsoftmax_kernel<<<(N + 255) / 256, 256, 0, stream>>>(agg2, b2, out, N);
}

// Round 2
// 357.621 us; speedup vs baseline: 1.5046x; 1.5046x over previous
//
#include <hip/hip_runtime.h>
#include <math.h>

// ---------------------------------------------------------------------------
// RGAT (2-layer graph attention) on MI355X — CSR-based, ZERO float atomics.
// N=50000, E=800000, IN=64, HID=64, OUT=8.
//   1. Build CSR by dst: int histogram -> block scan -> bucket fill.
//   2. gemm1 (wave/row, W in LDS, fused e_src/e_dst wave reductions).
//   3. agg64: one wave per dst node, lane=channel. max pass + accumulate
//      pass (exp, denom, edge-weighted gather of h[src]); fused bias+ReLU.
//   4. gemm2 (64x8).
//   5. agg8: one wave per dst node, lane-parallel over edges, 8-ch register
//      accumulators, wave-reduce; fused log_softmax -> d_out.
// Float atomics were the round-1 bottleneck (scatter64 = 177us, 200MB
// write-through). Gather aggregation writes only N*C floats.
// ---------------------------------------------------------------------------

// ---------------- CSR build ----------------

__global__ void __launch_bounds__(256) count_kernel(
    const int* __restrict__ dst, int* __restrict__ deg, int E)
{
    int e = blockIdx.x * 256 + threadIdx.x;
    if (e < E) atomicAdd(&deg[dst[e]], 1);
}

// partial sums of 256-chunks
__global__ void __launch_bounds__(256) scan1_kernel(
    const int* __restrict__ deg, int* __restrict__ part, int N)
{
    __shared__ int sm[256];
    int i = blockIdx.x * 256 + threadIdx.x;
    sm[threadIdx.x] = (i < N) ? deg[i] : 0;
    __syncthreads();
    for (int o = 128; o > 0; o >>= 1) {
        if (threadIdx.x < o) sm[threadIdx.x] += sm[threadIdx.x + o];
        __syncthreads();
    }
    if (threadIdx.x == 0) part[blockIdx.x] = sm[0];
}

// exclusive scan of block partials (nb <= 256), single block
__global__ void __launch_bounds__(256) scan2_kernel(int* __restrict__ part, int nb)
{
    __shared__ int sm[256];
    int t = threadIdx.x;
    int v = (t < nb) ? part[t] : 0;
    sm[t] = v;
    __syncthreads();
    for (int o = 1; o < 256; o <<= 1) {
        int add = (t >= o) ? sm[t - o] : 0;
        __syncthreads();
        sm[t] += add;
        __syncthreads();
    }
    if (t < nb) part[t] = sm[t] - v;   // exclusive
}

// per-element exclusive scan -> off[i]; also writes off[N] = E total
__global__ void __launch_bounds__(256) scan3_kernel(
    const int* __restrict__ deg, const int* __restrict__ part,
    int* __restrict__ off, int N)
{
    __shared__ int sm[256];
    int i = blockIdx.x * 256 + threadIdx.x;
    int t = threadIdx.x;
    int v = (i < N) ? deg[i] : 0;
    sm[t] = v;
    __syncthreads();
    for (int o = 1; o < 256; o <<= 1) {
        int add = (t >= o) ? sm[t - o] : 0;
        __syncthreads();
        sm[t] += add;
        __syncthreads();
    }
    if (i < N) off[i] = part[blockIdx.x] + sm[t] - v;
    if (i == N - 1) off[N] = part[blockIdx.x] + sm[t];
}

// bucket fill; consumes deg as cursor (atomicSub -> deg ends at 0)
__global__ void __launch_bounds__(256) fill_kernel(
    const int* __restrict__ src, const int* __restrict__ dst,
    const float* __restrict__ ev, const int* __restrict__ off,
    int* __restrict__ deg, int* __restrict__ csr_src,
    float* __restrict__ csr_ev, int E)
{
    int e = blockIdx.x * 256 + threadIdx.x;
    if (e >= E) return;
    int d = dst[e];
    int pos = off[d] + atomicSub(&deg[d], 1) - 1;
    csr_src[pos] = src[e];
    csr_ev[pos]  = ev[e];
}

// ---------------- dense transforms ----------------

// h = x @ W (64x64), es = h@a_src, ed = h@a_dst.  One wave per row.
__global__ void __launch_bounds__(256) gemm1_kernel(
    const float* __restrict__ x, const float* __restrict__ W,
    const float* __restrict__ a_src, const float* __restrict__ a_dst,
    float* __restrict__ h, float* __restrict__ es, float* __restrict__ ed, int N)
{
    __shared__ float Wl[64 * 64];
    __shared__ float asl[64], adl[64];
    for (int i = threadIdx.x; i < 64 * 64; i += 256) Wl[i] = W[i];
    if (threadIdx.x < 64) {
        asl[threadIdx.x] = a_src[threadIdx.x];
        adl[threadIdx.x] = a_dst[threadIdx.x];
    }
    __syncthreads();
    const int lane = threadIdx.x & 63;
    const int wid  = threadIdx.x >> 6;
    for (int row = blockIdx.x * 4 + wid; row < N; row += gridDim.x * 4) {
        float xv = x[(size_t)row * 64 + lane];
        float acc = 0.f;
        #pragma unroll
        for (int k = 0; k < 64; ++k) {
            float xk = __shfl(xv, k);
            acc += xk * Wl[k * 64 + lane];
        }
        h[(size_t)row * 64 + lane] = acc;
        float ps = acc * asl[lane];
        float pd = acc * adl[lane];
        #pragma unroll
        for (int off = 32; off > 0; off >>= 1) {
            ps += __shfl_down(ps, off);
            pd += __shfl_down(pd, off);
        }
        if (lane == 0) { es[row] = ps; ed[row] = pd; }
    }
}

// h2 = hid @ W2 (64x8), e2s/e2d per row.  8 rows per wave.
__global__ void __launch_bounds__(256) gemm2_kernel(
    const float* __restrict__ hid, const float* __restrict__ W,
    const float* __restrict__ a_src, const float* __restrict__ a_dst,
    float* __restrict__ h2, float* __restrict__ es, float* __restrict__ ed, int N)
{
    __shared__ float Wl[64 * 8];
    __shared__ float asl[8], adl[8];
    for (int i = threadIdx.x; i < 64 * 8; i += 256) Wl[i] = W[i];
    if (threadIdx.x < 8) {
        asl[threadIdx.x] = a_src[threadIdx.x];
        adl[threadIdx.x] = a_dst[threadIdx.x];
    }
    __syncthreads();
    const int lane = threadIdx.x & 63;
    const int wid  = threadIdx.x >> 6;
    const int r = lane >> 3, c = lane & 7;
    for (int base = (blockIdx.x * 4 + wid) * 8; base < N; base += gridDim.x * 32) {
        int row = base + r;
        float acc = 0.f;
        if (row < N) {
            #pragma unroll 8
            for (int k = 0; k < 64; ++k)
                acc += hid[(size_t)row * 64 + k] * Wl[k * 8 + c];
            h2[(size_t)row * 8 + c] = acc;
        }
        float ps = acc * asl[c];
        float pd = acc * adl[c];
        #pragma unroll
        for (int off = 4; off > 0; off >>= 1) {
            ps += __shfl_xor(ps, off);
            pd += __shfl_xor(pd, off);
        }
        if (row < N && c == 0) { es[row] = ps; ed[row] = pd; }
    }
}

// ---------------- aggregation (gather, no atomics) ----------------

// Layer 1: one wave per node, lane = channel (C=64). Fused bias+ReLU.
__global__ void __launch_bounds__(256) agg64_kernel(
    const int* __restrict__ off, const int* __restrict__ csr_src,
    const float* __restrict__ csr_ev, const float* __restrict__ es,
    const float* __restrict__ ed, const float* __restrict__ h,
    const float* __restrict__ b, float* __restrict__ outAgg, int N)
{
    const int wid = threadIdx.x >> 6, lane = threadIdx.x & 63;
    int n = blockIdx.x * 4 + wid;
    if (n >= N) return;
    const int beg = off[n], end = off[n + 1];
    const float edn = ed[n];

    // pass 1: lane-parallel max over logits
    float mx = -INFINITY;
    for (int i = beg + lane; i < end; i += 64) {
        float z = es[csr_src[i]] + edn;
        float l = z > 0.f ? z : 0.2f * z;
        mx = fmaxf(mx, l);
    }
    #pragma unroll
    for (int o = 32; o > 0; o >>= 1) mx = fmaxf(mx, __shfl_xor(mx, o));

    // pass 2: serial edges, lane = channel
    float acc = 0.f, den = 0.f;
    for (int i = beg; i < end; ++i) {
        int s = csr_src[i];                 // broadcast
        float z = es[s] + edn;
        float l = z > 0.f ? z : 0.2f * z;
        float exv = expf(l - mx);
        den += exv;
        acc += exv * csr_ev[i] * h[(size_t)s * 64 + lane];
    }
    float v = acc / (den + 1e-16f) + b[lane];
    outAgg[(size_t)n * 64 + lane] = v > 0.f ? v : 0.f;
}

// Layer 2 + log_softmax: one wave per node, lane-parallel edges, C=8.
__global__ void __launch_bounds__(256) agg8_lsm_kernel(
    const int* __restrict__ off, const int* __restrict__ csr_src,
    const float* __restrict__ csr_ev, const float* __restrict__ es,
    const float* __restrict__ ed, const float* __restrict__ h2,
    const float* __restrict__ b, float* __restrict__ out, int N)
{
    const int wid = threadIdx.x >> 6, lane = threadIdx.x & 63;
    int n = blockIdx.x * 4 + wid;
    if (n >= N) return;
    const int beg = off[n], end = off[n + 1];
    const float edn = ed[n];

    float mx = -INFINITY;
    for (int i = beg + lane; i < end; i += 64) {
        float z = es[csr_src[i]] + edn;
        float l = z > 0.f ? z : 0.2f * z;
        mx = fmaxf(mx, l);
    }
    #pragma unroll
    for (int o = 32; o > 0; o >>= 1) mx = fmaxf(mx, __shfl_xor(mx, o));

    float acc[8] = {0, 0, 0, 0, 0, 0, 0, 0};
    float den = 0.f;
    for (int i = beg + lane; i < end; i += 64) {
        int s = csr_src[i];
        float z = es[s] + edn;
        float l = z > 0.f ? z : 0.2f * z;
        float exv = expf(l - mx);
        den += exv;
        float w = exv * csr_ev[i];
        #pragma unroll
        for (int c = 0; c < 8; ++c) acc[c] += w * h2[(size_t)s * 8 + c];
    }
    #pragma unroll
    for (int o = 32; o > 0; o >>= 1) {
        den += __shfl_xor(den, o);
        #pragma unroll
        for (int c = 0; c < 8; ++c) acc[c] += __shfl_xor(acc[c], o);
    }
    float inv = 1.f / (den + 1e-16f);
    float v[8], vm = -1e30f;
    #pragma unroll
    for (int c = 0; c < 8; ++c) { v[c] = acc[c] * inv + b[c]; vm = fmaxf(vm, v[c]); }
    float s = 0.f;
    #pragma unroll
    for (int c = 0; c < 8; ++c) s += expf(v[c] - vm);
    float lse = vm + logf(s);
    if (lane < 8) out[(size_t)n * 8 + lane] = v[lane] - lse;
}

// ---------------------------------------------------------------------------

extern "C" void kernel_launch(void* const* d_in, const int* in_sizes, int n_in,
                              void* d_out, int out_size, void* d_ws, size_t ws_size,
                              hipStream_t stream)
{
    const float* x   = (const float*)d_in[0];
    const int*   ei  = (const int*)d_in[1];
    const float* ev  = (const float*)d_in[2];
    const float* W1  = (const float*)d_in[3];
    const float* a1s = (const float*)d_in[4];
    const float* a1d = (const float*)d_in[5];
    const float* b1  = (const float*)d_in[6];
    const float* W2  = (const float*)d_in[7];
    const float* a2s = (const float*)d_in[8];
    const float* a2d = (const float*)d_in[9];
    const float* b2  = (const float*)d_in[10];
    float* out = (float*)d_out;

    const int N = in_sizes[0] / 64;
    const int E = in_sizes[2];
    const int* srcp = ei;
    const int* dstp = ei + E;
    const int nb = (N + 255) / 256;        // 196 scan blocks (<=256)

    // Workspace layout:
    //   deg   int  N      (zeroed; consumed as cursor by fill)
    //   off   int  N+1
    //   part  int  256
    //   csrs  int  E
    //   csrv  f32  E
    //   es1   f32  N
    //   ed1   f32  N
    //   h1    f32  N*64   (layer2's h2/es2/ed2 alias here after agg64)
    //   agg1  f32  N*64
    int*   deg  = (int*)d_ws;
    int*   off  = deg + N;
    int*   part = off + N + 1;
    int*   csrs = part + 256;
    float* csrv = (float*)(csrs + E);
    float* es1  = csrv + E;
    float* ed1  = es1 + N;
    float* h1   = ed1 + N;
    float* agg1 = h1 + (size_t)N * 64;
    float* h2   = h1;                       // alias: h1 dead after agg64
    float* es2  = h1 + (size_t)N * 8;
    float* ed2  = es2 + N;

    hipMemsetAsync(deg, 0, (size_t)N * sizeof(int), stream);

    // CSR build
    count_kernel<<<(E + 255) / 256, 256, 0, stream>>>(dstp, deg, E);
    scan1_kernel<<<nb, 256, 0, stream>>>(deg, part, N);
    scan2_kernel<<<1, 256, 0, stream>>>(part, nb);
    scan3_kernel<<<nb, 256, 0, stream>>>(deg, part, off, N);
    fill_kernel<<<(E + 255) / 256, 256, 0, stream>>>(srcp, dstp, ev, off, deg, csrs, csrv, E);

    // Layer 1
    gemm1_kernel<<<2048, 256, 0, stream>>>(x, W1, a1s, a1d, h1, es1, ed1, N);
    agg64_kernel<<<(N + 3) / 4, 256, 0, stream>>>(off, csrs, csrv, es1, ed1, h1, b1, agg1, N);

    // Layer 2 (h2/es2/ed2 overwrite h1's storage)
    gemm2_kernel<<<1024, 256, 0, stream>>>(agg1, W2, a2s, a2d, h2, es2, ed2, N);
    agg8_lsm_kernel<<<(N + 3) / 4, 256, 0, stream>>>(off, csrs, csrv, es2, ed2, h2, b2, out, N);
}

// Round 3
// 324.519 us; speedup vs baseline: 1.6581x; 1.1020x over previous
//
#include <hip/hip_runtime.h>
#include <math.h>

// ---------------------------------------------------------------------------
// RGAT (2-layer graph attention) on MI355X — CSR gather, precomputed weights.
// N=50000, E=800000, IN=64, HID=64, OUT=8.
//   1. CSR build by dst (histogram -> scan -> bucket fill).
//   2. gemm1 (wave/row, W in LDS, fused e_src/e_dst wave reductions).
//   3. attn_kernel: wave/node, lane-parallel; writes final edge coefficient
//      w[i] = exp(l - max)/den * ev[i] in CSR order (all expf lives here).
//   4. agg64: wave/node, 4 edges/iter, 16 lanes/edge, float4 h loads;
//      shfl-combine; fused bias+ReLU.  (round-2 version burned ~25 VALU
//      instrs/edge on redundant expf -> 95us; this is ~3/edge)
//   5. gemm2, attn (layer 2), agg8+log_softmax (8 edges/iter, 8 lanes/edge).
// ---------------------------------------------------------------------------

// ---------------- CSR build ----------------

__global__ void __launch_bounds__(256) count_kernel(
    const int* __restrict__ dst, int* __restrict__ deg, int E)
{
    int e = blockIdx.x * 256 + threadIdx.x;
    if (e < E) atomicAdd(&deg[dst[e]], 1);
}

__global__ void __launch_bounds__(256) scan1_kernel(
    const int* __restrict__ deg, int* __restrict__ part, int N)
{
    __shared__ int sm[256];
    int i = blockIdx.x * 256 + threadIdx.x;
    sm[threadIdx.x] = (i < N) ? deg[i] : 0;
    __syncthreads();
    for (int o = 128; o > 0; o >>= 1) {
        if (threadIdx.x < o) sm[threadIdx.x] += sm[threadIdx.x + o];
        __syncthreads();
    }
    if (threadIdx.x == 0) part[blockIdx.x] = sm[0];
}

__global__ void __launch_bounds__(256) scan2_kernel(int* __restrict__ part, int nb)
{
    __shared__ int sm[256];
    int t = threadIdx.x;
    int v = (t < nb) ? part[t] : 0;
    sm[t] = v;
    __syncthreads();
    for (int o = 1; o < 256; o <<= 1) {
        int add = (t >= o) ? sm[t - o] : 0;
        __syncthreads();
        sm[t] += add;
        __syncthreads();
    }
    if (t < nb) part[t] = sm[t] - v;   // exclusive
}

__global__ void __launch_bounds__(256) scan3_kernel(
    const int* __restrict__ deg, const int* __restrict__ part,
    int* __restrict__ off, int N)
{
    __shared__ int sm[256];
    int i = blockIdx.x * 256 + threadIdx.x;
    int t = threadIdx.x;
    int v = (i < N) ? deg[i] : 0;
    sm[t] = v;
    __syncthreads();
    for (int o = 1; o < 256; o <<= 1) {
        int add = (t >= o) ? sm[t - o] : 0;
        __syncthreads();
        sm[t] += add;
        __syncthreads();
    }
    if (i < N) off[i] = part[blockIdx.x] + sm[t] - v;
    if (i == N - 1) off[N] = part[blockIdx.x] + sm[t];
}

__global__ void __launch_bounds__(256) fill_kernel(
    const int* __restrict__ src, const int* __restrict__ dst,
    const float* __restrict__ ev, const int* __restrict__ off,
    int* __restrict__ deg, int* __restrict__ csr_src,
    float* __restrict__ csr_ev, int E)
{
    int e = blockIdx.x * 256 + threadIdx.x;
    if (e >= E) return;
    int d = dst[e];
    int pos = off[d] + atomicSub(&deg[d], 1) - 1;
    csr_src[pos] = src[e];
    csr_ev[pos]  = ev[e];
}

// ---------------- dense transforms ----------------

__global__ void __launch_bounds__(256) gemm1_kernel(
    const float* __restrict__ x, const float* __restrict__ W,
    const float* __restrict__ a_src, const float* __restrict__ a_dst,
    float* __restrict__ h, float* __restrict__ es, float* __restrict__ ed, int N)
{
    __shared__ float Wl[64 * 64];
    __shared__ float asl[64], adl[64];
    for (int i = threadIdx.x; i < 64 * 64; i += 256) Wl[i] = W[i];
    if (threadIdx.x < 64) {
        asl[threadIdx.x] = a_src[threadIdx.x];
        adl[threadIdx.x] = a_dst[threadIdx.x];
    }
    __syncthreads();
    const int lane = threadIdx.x & 63;
    const int wid  = threadIdx.x >> 6;
    for (int row = blockIdx.x * 4 + wid; row < N; row += gridDim.x * 4) {
        float xv = x[(size_t)row * 64 + lane];
        float acc = 0.f;
        #pragma unroll
        for (int k = 0; k < 64; ++k) {
            float xk = __shfl(xv, k);
            acc += xk * Wl[k * 64 + lane];
        }
        h[(size_t)row * 64 + lane] = acc;
        float ps = acc * asl[lane];
        float pd = acc * adl[lane];
        #pragma unroll
        for (int off = 32; off > 0; off >>= 1) {
            ps += __shfl_down(ps, off);
            pd += __shfl_down(pd, off);
        }
        if (lane == 0) { es[row] = ps; ed[row] = pd; }
    }
}

__global__ void __launch_bounds__(256) gemm2_kernel(
    const float* __restrict__ hid, const float* __restrict__ W,
    const float* __restrict__ a_src, const float* __restrict__ a_dst,
    float* __restrict__ h2, float* __restrict__ es, float* __restrict__ ed, int N)
{
    __shared__ float Wl[64 * 8];
    __shared__ float asl[8], adl[8];
    for (int i = threadIdx.x; i < 64 * 8; i += 256) Wl[i] = W[i];
    if (threadIdx.x < 8) {
        asl[threadIdx.x] = a_src[threadIdx.x];
        adl[threadIdx.x] = a_dst[threadIdx.x];
    }
    __syncthreads();
    const int lane = threadIdx.x & 63;
    const int wid  = threadIdx.x >> 6;
    const int r = lane >> 3, c = lane & 7;
    for (int base = (blockIdx.x * 4 + wid) * 8; base < N; base += gridDim.x * 32) {
        int row = base + r;
        float acc = 0.f;
        if (row < N) {
            #pragma unroll 8
            for (int k = 0; k < 64; ++k)
                acc += hid[(size_t)row * 64 + k] * Wl[k * 8 + c];
            h2[(size_t)row * 8 + c] = acc;
        }
        float ps = acc * asl[c];
        float pd = acc * adl[c];
        #pragma unroll
        for (int off = 4; off > 0; off >>= 1) {
            ps += __shfl_xor(ps, off);
            pd += __shfl_xor(pd, off);
        }
        if (row < N && c == 0) { es[row] = ps; ed[row] = pd; }
    }
}

// ---------------- attention coefficients (per layer) ----------------
// w[i] = exp(leaky(es[src_i]+ed[n]) - max) / (den+1e-16) * ev[i], CSR order.
__global__ void __launch_bounds__(256) attn_kernel(
    const int* __restrict__ off, const int* __restrict__ csr_src,
    const float* __restrict__ csr_ev, const float* __restrict__ es,
    const float* __restrict__ ed, float* __restrict__ w, int N)
{
    const int wid = threadIdx.x >> 6, lane = threadIdx.x & 63;
    int n = blockIdx.x * 4 + wid;
    if (n >= N) return;
    const int beg = off[n], end = off[n + 1];
    const float edn = ed[n];

    float mx = -INFINITY;
    for (int i = beg + lane; i < end; i += 64) {
        float z = es[csr_src[i]] + edn;
        float l = z > 0.f ? z : 0.2f * z;
        w[i] = l;
        mx = fmaxf(mx, l);
    }
    #pragma unroll
    for (int o = 32; o > 0; o >>= 1) mx = fmaxf(mx, __shfl_xor(mx, o));

    float den = 0.f;
    for (int i = beg + lane; i < end; i += 64) {
        float exv = expf(w[i] - mx);
        w[i] = exv;
        den += exv;
    }
    #pragma unroll
    for (int o = 32; o > 0; o >>= 1) den += __shfl_xor(den, o);

    float inv = 1.f / (den + 1e-16f);
    for (int i = beg + lane; i < end; i += 64)
        w[i] = w[i] * inv * csr_ev[i];
}

// ---------------- aggregation ----------------

// Layer 1 (C=64): wave/node, 4 edges per iter, 16 lanes/edge, float4 loads.
__global__ void __launch_bounds__(256) agg64_kernel(
    const int* __restrict__ off, const int* __restrict__ csr_src,
    const float* __restrict__ w, const float* __restrict__ h,
    const float* __restrict__ b, float* __restrict__ outAgg, int N)
{
    const int wid = threadIdx.x >> 6, lane = threadIdx.x & 63;
    int n = blockIdx.x * 4 + wid;
    if (n >= N) return;
    const int beg = off[n], end = off[n + 1];
    const int g  = lane >> 4;        // edge slot 0..3
    const int c4 = lane & 15;        // channels c4*4 .. c4*4+3

    float4 acc = make_float4(0.f, 0.f, 0.f, 0.f);
    for (int i = beg; i < end; i += 4) {
        int e = i + g;
        if (e < end) {
            int s = csr_src[e];
            float wt = w[e];
            const float4 hv = *(const float4*)&h[(size_t)s * 64 + (c4 << 2)];
            acc.x += wt * hv.x;
            acc.y += wt * hv.y;
            acc.z += wt * hv.z;
            acc.w += wt * hv.w;
        }
    }
    // combine 4 edge groups (flip g bits: lane bits 4 and 5)
    acc.x += __shfl_xor(acc.x, 16); acc.y += __shfl_xor(acc.y, 16);
    acc.z += __shfl_xor(acc.z, 16); acc.w += __shfl_xor(acc.w, 16);
    acc.x += __shfl_xor(acc.x, 32); acc.y += __shfl_xor(acc.y, 32);
    acc.z += __shfl_xor(acc.z, 32); acc.w += __shfl_xor(acc.w, 32);

    if (g == 0) {
        const float4 bb = *(const float4*)&b[c4 << 2];
        float4 v;
        v.x = fmaxf(acc.x + bb.x, 0.f);
        v.y = fmaxf(acc.y + bb.y, 0.f);
        v.z = fmaxf(acc.z + bb.z, 0.f);
        v.w = fmaxf(acc.w + bb.w, 0.f);
        *(float4*)&outAgg[(size_t)n * 64 + (c4 << 2)] = v;
    }
}

// Layer 2 (C=8) + log_softmax: wave/node, 8 edges/iter, 8 lanes/edge.
__global__ void __launch_bounds__(256) agg8_lsm_kernel(
    const int* __restrict__ off, const int* __restrict__ csr_src,
    const float* __restrict__ w, const float* __restrict__ h2,
    const float* __restrict__ b, float* __restrict__ out, int N)
{
    const int wid = threadIdx.x >> 6, lane = threadIdx.x & 63;
    int n = blockIdx.x * 4 + wid;
    if (n >= N) return;
    const int beg = off[n], end = off[n + 1];
    const int g = lane >> 3;     // edge slot 0..7
    const int c = lane & 7;      // channel

    float acc = 0.f;
    for (int i = beg; i < end; i += 8) {
        int e = i + g;
        if (e < end) {
            int s = csr_src[e];
            acc += w[e] * h2[(size_t)s * 8 + c];
        }
    }
    // combine 8 edge groups (flip g bits: lane bits 3,4,5)
    acc += __shfl_xor(acc, 8);
    acc += __shfl_xor(acc, 16);
    acc += __shfl_xor(acc, 32);

    // log_softmax across the 8 channels (within each aligned 8-lane group)
    float v = acc + b[c];
    float vm = v;
    vm = fmaxf(vm, __shfl_xor(vm, 1));
    vm = fmaxf(vm, __shfl_xor(vm, 2));
    vm = fmaxf(vm, __shfl_xor(vm, 4));
    float s = expf(v - vm);
    s += __shfl_xor(s, 1);
    s += __shfl_xor(s, 2);
    s += __shfl_xor(s, 4);
    float lse = vm + logf(s);
    if (lane < 8) out[(size_t)n * 8 + lane] = v - lse;
}

// ---------------------------------------------------------------------------

extern "C" void kernel_launch(void* const* d_in, const int* in_sizes, int n_in,
                              void* d_out, int out_size, void* d_ws, size_t ws_size,
                              hipStream_t stream)
{
    const float* x   = (const float*)d_in[0];
    const int*   ei  = (const int*)d_in[1];
    const float* ev  = (const float*)d_in[2];
    const float* W1  = (const float*)d_in[3];
    const float* a1s = (const float*)d_in[4];
    const float* a1d = (const float*)d_in[5];
    const float* b1  = (const float*)d_in[6];
    const float* W2  = (const float*)d_in[7];
    const float* a2s = (const float*)d_in[8];
    const float* a2d = (const float*)d_in[9];
    const float* b2  = (const float*)d_in[10];
    float* out = (float*)d_out;

    const int N = in_sizes[0] / 64;
    const int E = in_sizes[2];
    const int* srcp = ei;
    const int* dstp = ei + E;
    const int nb = (N + 255) / 256;

    // Workspace: deg N | off N+1 | part 256 | csrs E | csrv E | wbuf E |
    //            es1 N | ed1 N | h1 64N | agg1 64N   (h2/es2/ed2 alias h1)
    int*   deg  = (int*)d_ws;
    int*   off  = deg + N;
    int*   part = off + N + 1;
    int*   csrs = part + 256;
    float* csrv = (float*)(csrs + E);
    float* wbuf = csrv + E;
    float* es1  = wbuf + E;
    float* ed1  = es1 + N;
    float* h1   = ed1 + N;
    float* agg1 = h1 + (size_t)N * 64;
    float* h2   = h1;                      // h1 dead after agg64
    float* es2  = h1 + (size_t)N * 8;
    float* ed2  = es2 + N;

    hipMemsetAsync(deg, 0, (size_t)N * sizeof(int), stream);

    // CSR build
    count_kernel<<<(E + 255) / 256, 256, 0, stream>>>(dstp, deg, E);
    scan1_kernel<<<nb, 256, 0, stream>>>(deg, part, N);
    scan2_kernel<<<1, 256, 0, stream>>>(part, nb);
    scan3_kernel<<<nb, 256, 0, stream>>>(deg, part, off, N);
    fill_kernel<<<(E + 255) / 256, 256, 0, stream>>>(srcp, dstp, ev, off, deg, csrs, csrv, E);

    // Layer 1
    gemm1_kernel<<<2048, 256, 0, stream>>>(x, W1, a1s, a1d, h1, es1, ed1, N);
    attn_kernel<<<(N + 3) / 4, 256, 0, stream>>>(off, csrs, csrv, es1, ed1, wbuf, N);
    agg64_kernel<<<(N + 3) / 4, 256, 0, stream>>>(off, csrs, wbuf, h1, b1, agg1, N);

    // Layer 2
    gemm2_kernel<<<1024, 256, 0, stream>>>(agg1, W2, a2s, a2d, h2, es2, ed2, N);
    attn_kernel<<<(N + 3) / 4, 256, 0, stream>>>(off, csrs, csrv, es2, ed2, wbuf, N);
    agg8_lsm_kernel<<<(N + 3) / 4, 256, 0, stream>>>(off, csrs, wbuf, h2, b2, out, N);
}

// Round 4
// 274.324 us; speedup vs baseline: 1.9615x; 1.1830x over previous
//
#include <hip/hip_runtime.h>
#include <math.h>

// ---------------------------------------------------------------------------
// RGAT (2-layer graph attention) on MI355X — CSR gather, radix-partition build.
// N=50000, E=800000, IN=64, HID=64, OUT=8.
// Round-3 profile: fill_kernel wrote 82MB for 6.4MB payload (random dword
// scatter from 8 XCDs -> partial-line writeback amplification, ~60us).
// Replaced with 2-level partition: coarse buckets of 256 nodes (coalesced
// run writes), then per-bucket fine placement (32KB window, XCD-local).
// csr_kernel also emits off[] (removes old count+scan chain).
// ---------------------------------------------------------------------------

#define CHUNK 4096   // edges per partition workgroup
#define NBKT  256    // coarse buckets (dst>>8), 196 used for N=50000

// ---------------- CSR build ----------------

__global__ void __launch_bounds__(256) hist_kernel(
    const int* __restrict__ dst, int* __restrict__ hist, int E)
{
    __shared__ int lh[NBKT];
    int t = threadIdx.x;
    lh[t] = 0;
    __syncthreads();
    int e0 = blockIdx.x * CHUNK;
    int cnt = min(CHUNK, E - e0);
    for (int i = t; i < cnt; i += 256)
        atomicAdd(&lh[dst[e0 + i] >> 8], 1);
    __syncthreads();
    if (lh[t]) atomicAdd(&hist[t], lh[t]);
}

// single block: exclusive scan of 256 bucket counts -> boff[257]; cursor copy
__global__ void __launch_bounds__(256) bscan_kernel(
    const int* __restrict__ hist, int* __restrict__ boff,
    int* __restrict__ cursor)
{
    __shared__ int sm[256];
    int t = threadIdx.x;
    int v = hist[t];
    sm[t] = v;
    __syncthreads();
    for (int o = 1; o < 256; o <<= 1) {
        int add = (t >= o) ? sm[t - o] : 0;
        __syncthreads();
        sm[t] += add;
        __syncthreads();
    }
    int excl = sm[t] - v;
    boff[t] = excl;
    cursor[t] = excl;
    if (t == 255) boff[256] = sm[255];
}

// partition: reorder chunk in LDS by bucket, write coalesced runs of packed
// records:  low32 = src(16) | dloc(8)<<16 | bucket(8)<<24 ; high32 = ev bits.
__global__ void __launch_bounds__(256) part_kernel(
    const int* __restrict__ src, const int* __restrict__ dst,
    const float* __restrict__ ev, int* __restrict__ cursor,
    unsigned long long* __restrict__ ped, int E)
{
    __shared__ int lhist[NBKT], lbase[NBKT], lcur[NBKT], gbase[NBKT];
    __shared__ unsigned long long buf[CHUNK];
    int t = threadIdx.x;
    int e0 = blockIdx.x * CHUNK;
    int cnt = min(CHUNK, E - e0);
    lhist[t] = 0;
    __syncthreads();
    for (int i = t; i < cnt; i += 256)
        atomicAdd(&lhist[dst[e0 + i] >> 8], 1);
    __syncthreads();
    int myc = lhist[t];
    lbase[t] = myc;
    __syncthreads();
    for (int o = 1; o < 256; o <<= 1) {
        int add = (t >= o) ? lbase[t - o] : 0;
        __syncthreads();
        lbase[t] += add;
        __syncthreads();
    }
    int excl = lbase[t] - myc;
    gbase[t] = myc ? atomicAdd(&cursor[t], myc) : 0;
    __syncthreads();
    lbase[t] = excl;
    lcur[t] = excl;
    __syncthreads();
    for (int i = t; i < cnt; i += 256) {
        int e = e0 + i;
        int d = dst[e];
        int b = d >> 8;
        unsigned p = (unsigned)src[e] | ((unsigned)(d & 255) << 16)
                   | ((unsigned)b << 24);
        unsigned long long q = (unsigned long long)p
                   | ((unsigned long long)__float_as_uint(ev[e]) << 32);
        int r = atomicAdd(&lcur[b], 1);
        buf[r] = q;
    }
    __syncthreads();
    for (int i = t; i < cnt; i += 256) {
        unsigned long long q = buf[i];
        int b = (int)((q >> 24) & 255);
        ped[gbase[b] + i - lbase[b]] = q;
    }
}

// one workgroup per bucket: fine placement within [boff[b], boff[b+1]) and
// off[] emission (node offsets = bucket base + LDS scan of per-node counts).
__global__ void __launch_bounds__(256) csr_kernel(
    const unsigned long long* __restrict__ ped, const int* __restrict__ boff,
    int* __restrict__ off, int* __restrict__ csrs, float* __restrict__ csrv,
    int N, int E)
{
    __shared__ int cl[256], sc[256], cur[256];
    int b = blockIdx.x, t = threadIdx.x;
    int begin = boff[b], endb = boff[b + 1];
    cl[t] = 0;
    __syncthreads();
    for (int i = begin + t; i < endb; i += 256)
        atomicAdd(&cl[(int)((ped[i] >> 16) & 255)], 1);
    __syncthreads();
    int myc = cl[t];
    sc[t] = myc;
    __syncthreads();
    for (int o = 1; o < 256; o <<= 1) {
        int add = (t >= o) ? sc[t - o] : 0;
        __syncthreads();
        sc[t] += add;
        __syncthreads();
    }
    int excl = sc[t] - myc;
    int node = b * 256 + t;
    if (node < N) off[node] = begin + excl;
    if (b == 0 && t == 0) off[N] = E;
    cur[t] = begin + excl;
    __syncthreads();
    for (int i = begin + t; i < endb; i += 256) {
        unsigned long long q = ped[i];
        int dloc = (int)((q >> 16) & 255);
        int pos = atomicAdd(&cur[dloc], 1);
        csrs[pos] = (int)(q & 0xFFFF);
        csrv[pos] = __uint_as_float((unsigned)(q >> 32));
    }
}

// ---------------- dense transforms ----------------

__global__ void __launch_bounds__(256) gemm1_kernel(
    const float* __restrict__ x, const float* __restrict__ W,
    const float* __restrict__ a_src, const float* __restrict__ a_dst,
    float* __restrict__ h, float* __restrict__ es, float* __restrict__ ed, int N)
{
    __shared__ float Wl[64 * 64];
    __shared__ float asl[64], adl[64];
    for (int i = threadIdx.x; i < 64 * 64; i += 256) Wl[i] = W[i];
    if (threadIdx.x < 64) {
        asl[threadIdx.x] = a_src[threadIdx.x];
        adl[threadIdx.x] = a_dst[threadIdx.x];
    }
    __syncthreads();
    const int lane = threadIdx.x & 63;
    const int wid  = threadIdx.x >> 6;
    for (int row = blockIdx.x * 4 + wid; row < N; row += gridDim.x * 4) {
        float xv = x[(size_t)row * 64 + lane];
        float acc = 0.f;
        #pragma unroll
        for (int k = 0; k < 64; ++k) {
            float xk = __shfl(xv, k);
            acc += xk * Wl[k * 64 + lane];
        }
        h[(size_t)row * 64 + lane] = acc;
        float ps = acc * asl[lane];
        float pd = acc * adl[lane];
        #pragma unroll
        for (int off = 32; off > 0; off >>= 1) {
            ps += __shfl_down(ps, off);
            pd += __shfl_down(pd, off);
        }
        if (lane == 0) { es[row] = ps; ed[row] = pd; }
    }
}

__global__ void __launch_bounds__(256) gemm2_kernel(
    const float* __restrict__ hid, const float* __restrict__ W,
    const float* __restrict__ a_src, const float* __restrict__ a_dst,
    float* __restrict__ h2, float* __restrict__ es, float* __restrict__ ed, int N)
{
    __shared__ float Wl[64 * 8];
    __shared__ float asl[8], adl[8];
    for (int i = threadIdx.x; i < 64 * 8; i += 256) Wl[i] = W[i];
    if (threadIdx.x < 8) {
        asl[threadIdx.x] = a_src[threadIdx.x];
        adl[threadIdx.x] = a_dst[threadIdx.x];
    }
    __syncthreads();
    const int lane = threadIdx.x & 63;
    const int wid  = threadIdx.x >> 6;
    const int r = lane >> 3, c = lane & 7;
    for (int base = (blockIdx.x * 4 + wid) * 8; base < N; base += gridDim.x * 32) {
        int row = base + r;
        float acc = 0.f;
        if (row < N) {
            #pragma unroll 8
            for (int k = 0; k < 64; ++k)
                acc += hid[(size_t)row * 64 + k] * Wl[k * 8 + c];
            h2[(size_t)row * 8 + c] = acc;
        }
        float ps = acc * asl[c];
        float pd = acc * adl[c];
        #pragma unroll
        for (int off = 4; off > 0; off >>= 1) {
            ps += __shfl_xor(ps, off);
            pd += __shfl_xor(pd, off);
        }
        if (row < N && c == 0) { es[row] = ps; ed[row] = pd; }
    }
}

// ---------------- attention coefficients ----------------
__global__ void __launch_bounds__(256) attn_kernel(
    const int* __restrict__ off, const int* __restrict__ csr_src,
    const float* __restrict__ csr_ev, const float* __restrict__ es,
    const float* __restrict__ ed, float* __restrict__ w, int N)
{
    const int wid = threadIdx.x >> 6, lane = threadIdx.x & 63;
    int n = blockIdx.x * 4 + wid;
    if (n >= N) return;
    const int beg = off[n], end = off[n + 1];
    const float edn = ed[n];

    float mx = -INFINITY;
    for (int i = beg + lane; i < end; i += 64) {
        float z = es[csr_src[i]] + edn;
        float l = z > 0.f ? z : 0.2f * z;
        w[i] = l;
        mx = fmaxf(mx, l);
    }
    #pragma unroll
    for (int o = 32; o > 0; o >>= 1) mx = fmaxf(mx, __shfl_xor(mx, o));

    float den = 0.f;
    for (int i = beg + lane; i < end; i += 64) {
        float exv = expf(w[i] - mx);
        w[i] = exv;
        den += exv;
    }
    #pragma unroll
    for (int o = 32; o > 0; o >>= 1) den += __shfl_xor(den, o);

    float inv = 1.f / (den + 1e-16f);
    for (int i = beg + lane; i < end; i += 64)
        w[i] = w[i] * inv * csr_ev[i];
}

// ---------------- aggregation ----------------

__global__ void __launch_bounds__(256) agg64_kernel(
    const int* __restrict__ off, const int* __restrict__ csr_src,
    const float* __restrict__ w, const float* __restrict__ h,
    const float* __restrict__ b, float* __restrict__ outAgg, int N)
{
    const int wid = threadIdx.x >> 6, lane = threadIdx.x & 63;
    int n = blockIdx.x * 4 + wid;
    if (n >= N) return;
    const int beg = off[n], end = off[n + 1];
    const int g  = lane >> 4;
    const int c4 = lane & 15;

    float4 acc = make_float4(0.f, 0.f, 0.f, 0.f);
    for (int i = beg; i < end; i += 4) {
        int e = i + g;
        if (e < end) {
            int s = csr_src[e];
            float wt = w[e];
            const float4 hv = *(const float4*)&h[(size_t)s * 64 + (c4 << 2)];
            acc.x += wt * hv.x;
            acc.y += wt * hv.y;
            acc.z += wt * hv.z;
            acc.w += wt * hv.w;
        }
    }
    acc.x += __shfl_xor(acc.x, 16); acc.y += __shfl_xor(acc.y, 16);
    acc.z += __shfl_xor(acc.z, 16); acc.w += __shfl_xor(acc.w, 16);
    acc.x += __shfl_xor(acc.x, 32); acc.y += __shfl_xor(acc.y, 32);
    acc.z += __shfl_xor(acc.z, 32); acc.w += __shfl_xor(acc.w, 32);

    if (g == 0) {
        const float4 bb = *(const float4*)&b[c4 << 2];
        float4 v;
        v.x = fmaxf(acc.x + bb.x, 0.f);
        v.y = fmaxf(acc.y + bb.y, 0.f);
        v.z = fmaxf(acc.z + bb.z, 0.f);
        v.w = fmaxf(acc.w + bb.w, 0.f);
        *(float4*)&outAgg[(size_t)n * 64 + (c4 << 2)] = v;
    }
}

__global__ void __launch_bounds__(256) agg8_lsm_kernel(
    const int* __restrict__ off, const int* __restrict__ csr_src,
    const float* __restrict__ w, const float* __restrict__ h2,
    const float* __restrict__ b, float* __restrict__ out, int N)
{
    const int wid = threadIdx.x >> 6, lane = threadIdx.x & 63;
    int n = blockIdx.x * 4 + wid;
    if (n >= N) return;
    const int beg = off[n], end = off[n + 1];
    const int g = lane >> 3;
    const int c = lane & 7;

    float acc = 0.f;
    for (int i = beg; i < end; i += 8) {
        int e = i + g;
        if (e < end) {
            int s = csr_src[e];
            acc += w[e] * h2[(size_t)s * 8 + c];
        }
    }
    acc += __shfl_xor(acc, 8);
    acc += __shfl_xor(acc, 16);
    acc += __shfl_xor(acc, 32);

    float v = acc + b[c];
    float vm = v;
    vm = fmaxf(vm, __shfl_xor(vm, 1));
    vm = fmaxf(vm, __shfl_xor(vm, 2));
    vm = fmaxf(vm, __shfl_xor(vm, 4));
    float s = expf(v - vm);
    s += __shfl_xor(s, 1);
    s += __shfl_xor(s, 2);
    s += __shfl_xor(s, 4);
    float lse = vm + logf(s);
    if (lane < 8) out[(size_t)n * 8 + lane] = v - lse;
}

// ---------------------------------------------------------------------------

extern "C" void kernel_launch(void* const* d_in, const int* in_sizes, int n_in,
                              void* d_out, int out_size, void* d_ws, size_t ws_size,
                              hipStream_t stream)
{
    const float* x   = (const float*)d_in[0];
    const int*   ei  = (const int*)d_in[1];
    const float* ev  = (const float*)d_in[2];
    const float* W1  = (const float*)d_in[3];
    const float* a1s = (const float*)d_in[4];
    const float* a1d = (const float*)d_in[5];
    const float* b1  = (const float*)d_in[6];
    const float* W2  = (const float*)d_in[7];
    const float* a2s = (const float*)d_in[8];
    const float* a2d = (const float*)d_in[9];
    const float* b2  = (const float*)d_in[10];
    float* out = (float*)d_out;

    const int N = in_sizes[0] / 64;
    const int E = in_sizes[2];
    const int* srcp = ei;
    const int* dstp = ei + E;
    const int nchunks = (E + CHUNK - 1) / CHUNK;
    const int nbuck = (N + 255) / 256;

    // Workspace (8B-aligned first):
    //  ped E ull | hist 256 | boff 257 | cursor 256 | off N+1 |
    //  csrs E | csrv E | wbuf E | es1 N | ed1 N | h1 64N | agg1 64N
    unsigned long long* ped = (unsigned long long*)d_ws;
    int*   hist   = (int*)(ped + E);
    int*   boff   = hist + 256;
    int*   cursor = boff + 257;
    int*   off    = cursor + 256;          // N+1
    int*   csrs   = off + N + 1;
    float* csrv   = (float*)(csrs + E);
    float* wbuf   = csrv + E;
    float* es1    = wbuf + E;
    float* ed1    = es1 + N;
    float* h1     = ed1 + N;
    float* agg1   = h1 + (size_t)N * 64;
    float* h2     = h1;                     // h1 dead after agg64
    float* es2    = h1 + (size_t)N * 8;
    float* ed2    = es2 + N;

    hipMemsetAsync(hist, 0, 256 * sizeof(int), stream);

    // CSR build (radix partition)
    hist_kernel<<<nchunks, 256, 0, stream>>>(dstp, hist, E);
    bscan_kernel<<<1, 256, 0, stream>>>(hist, boff, cursor);
    part_kernel<<<nchunks, 256, 0, stream>>>(srcp, dstp, ev, cursor, ped, E);
    csr_kernel<<<nbuck, 256, 0, stream>>>(ped, boff, off, csrs, csrv, N, E);

    // Layer 1
    gemm1_kernel<<<2048, 256, 0, stream>>>(x, W1, a1s, a1d, h1, es1, ed1, N);
    attn_kernel<<<(N + 3) / 4, 256, 0, stream>>>(off, csrs, csrv, es1, ed1, wbuf, N);
    agg64_kernel<<<(N + 3) / 4, 256, 0, stream>>>(off, csrs, wbuf, h1, b1, agg1, N);

    // Layer 2
    gemm2_kernel<<<1024, 256, 0, stream>>>(agg1, W2, a2s, a2d, h2, es2, ed2, N);
    attn_kernel<<<(N + 3) / 4, 256, 0, stream>>>(off, csrs, csrv, es2, ed2, wbuf, N);
    agg8_lsm_kernel<<<(N + 3) / 4, 256, 0, stream>>>(off, csrs, wbuf, h2, b2, out, N);
}

// Round 5
// 238.777 us; speedup vs baseline: 2.2535x; 1.1489x over previous
//
#include <hip/hip_runtime.h>
#include <math.h>

// ---------------------------------------------------------------------------
// RGAT (2-layer graph attention) on MI355X — CSR gather, radix-partition build.
// N=50000, E=800000, IN=64, HID=64, OUT=8.
// Round-4 profile: gemm1 was 53us (shfl-broadcast structure: 3 cross-lane/LDS
// ops per FMA, VALUBusy 19%). Replaced with register-tiled GEMM: 64x64 block
// tile, 4x4 micro-tile/thread, Xt transposed+swizzled in LDS, fused es/ed.
// ---------------------------------------------------------------------------

#define CHUNK 4096   // edges per partition workgroup
#define NBKT  256    // coarse buckets (dst>>8), 196 used for N=50000

// ---------------- CSR build ----------------

__global__ void __launch_bounds__(256) hist_kernel(
    const int* __restrict__ dst, int* __restrict__ hist, int E)
{
    __shared__ int lh[NBKT];
    int t = threadIdx.x;
    lh[t] = 0;
    __syncthreads();
    int e0 = blockIdx.x * CHUNK;
    int cnt = min(CHUNK, E - e0);
    for (int i = t; i < cnt; i += 256)
        atomicAdd(&lh[dst[e0 + i] >> 8], 1);
    __syncthreads();
    if (lh[t]) atomicAdd(&hist[t], lh[t]);
}

__global__ void __launch_bounds__(256) bscan_kernel(
    const int* __restrict__ hist, int* __restrict__ boff,
    int* __restrict__ cursor)
{
    __shared__ int sm[256];
    int t = threadIdx.x;
    int v = hist[t];
    sm[t] = v;
    __syncthreads();
    for (int o = 1; o < 256; o <<= 1) {
        int add = (t >= o) ? sm[t - o] : 0;
        __syncthreads();
        sm[t] += add;
        __syncthreads();
    }
    int excl = sm[t] - v;
    boff[t] = excl;
    cursor[t] = excl;
    if (t == 255) boff[256] = sm[255];
}

__global__ void __launch_bounds__(256) part_kernel(
    const int* __restrict__ src, const int* __restrict__ dst,
    const float* __restrict__ ev, int* __restrict__ cursor,
    unsigned long long* __restrict__ ped, int E)
{
    __shared__ int lhist[NBKT], lbase[NBKT], lcur[NBKT], gbase[NBKT];
    __shared__ unsigned long long buf[CHUNK];
    int t = threadIdx.x;
    int e0 = blockIdx.x * CHUNK;
    int cnt = min(CHUNK, E - e0);
    lhist[t] = 0;
    __syncthreads();
    for (int i = t; i < cnt; i += 256)
        atomicAdd(&lhist[dst[e0 + i] >> 8], 1);
    __syncthreads();
    int myc = lhist[t];
    lbase[t] = myc;
    __syncthreads();
    for (int o = 1; o < 256; o <<= 1) {
        int add = (t >= o) ? lbase[t - o] : 0;
        __syncthreads();
        lbase[t] += add;
        __syncthreads();
    }
    int excl = lbase[t] - myc;
    gbase[t] = myc ? atomicAdd(&cursor[t], myc) : 0;
    __syncthreads();
    lbase[t] = excl;
    lcur[t] = excl;
    __syncthreads();
    for (int i = t; i < cnt; i += 256) {
        int e = e0 + i;
        int d = dst[e];
        int b = d >> 8;
        unsigned p = (unsigned)src[e] | ((unsigned)(d & 255) << 16)
                   | ((unsigned)b << 24);
        unsigned long long q = (unsigned long long)p
                   | ((unsigned long long)__float_as_uint(ev[e]) << 32);
        int r = atomicAdd(&lcur[b], 1);
        buf[r] = q;
    }
    __syncthreads();
    for (int i = t; i < cnt; i += 256) {
        unsigned long long q = buf[i];
        int b = (int)((q >> 24) & 255);
        ped[gbase[b] + i - lbase[b]] = q;
    }
}

__global__ void __launch_bounds__(256) csr_kernel(
    const unsigned long long* __restrict__ ped, const int* __restrict__ boff,
    int* __restrict__ off, int* __restrict__ csrs, float* __restrict__ csrv,
    int N, int E)
{
    __shared__ int cl[256], sc[256], cur[256];
    int b = blockIdx.x, t = threadIdx.x;
    int begin = boff[b], endb = boff[b + 1];
    cl[t] = 0;
    __syncthreads();
    for (int i = begin + t; i < endb; i += 256)
        atomicAdd(&cl[(int)((ped[i] >> 16) & 255)], 1);
    __syncthreads();
    int myc = cl[t];
    sc[t] = myc;
    __syncthreads();
    for (int o = 1; o < 256; o <<= 1) {
        int add = (t >= o) ? sc[t - o] : 0;
        __syncthreads();
        sc[t] += add;
        __syncthreads();
    }
    int excl = sc[t] - myc;
    int node = b * 256 + t;
    if (node < N) off[node] = begin + excl;
    if (b == 0 && t == 0) off[N] = E;
    cur[t] = begin + excl;
    __syncthreads();
    for (int i = begin + t; i < endb; i += 256) {
        unsigned long long q = ped[i];
        int dloc = (int)((q >> 16) & 255);
        int pos = atomicAdd(&cur[dloc], 1);
        csrs[pos] = (int)(q & 0xFFFF);
        csrv[pos] = __uint_as_float((unsigned)(q >> 32));
    }
}

// ---------------- dense transforms ----------------

// Register-tiled GEMM: block = 64 rows x 64 cols, thread = 4x4 micro-tile.
// Xt in LDS transposed [k][row] with XOR swizzle on the 4-row group so the
// per-k ds_read_b128 of 4 rows is conflict-free. Fused es/ed reductions.
__global__ void __launch_bounds__(256) gemm1_kernel(
    const float* __restrict__ x, const float* __restrict__ W,
    const float* __restrict__ a_src, const float* __restrict__ a_dst,
    float* __restrict__ h, float* __restrict__ es, float* __restrict__ ed, int N)
{
    __shared__ float4 Wl[64 * 16];   // W[k][c], float4 chunks, k-major
    __shared__ float  Xt[64 * 64];   // Xt[k][row ^ swz(k)]
    const int t  = threadIdx.x;
    const int n0 = blockIdx.x * 64;

    #pragma unroll
    for (int i = 0; i < 4; ++i)
        Wl[t + i * 256] = ((const float4*)W)[t + i * 256];

    #pragma unroll
    for (int i = 0; i < 4; ++i) {
        int f   = t + i * 256;        // float4 slot in 64rows x 16chunks
        int row = f >> 4, kq = f & 15;
        int grow = n0 + row;
        float4 v = make_float4(0.f, 0.f, 0.f, 0.f);
        if (grow < N) v = ((const float4*)x)[(size_t)grow * 16 + kq];
        int rs = row ^ ((kq & 3) << 2);   // swizzle by (k>>2)&3
        Xt[(kq * 4 + 0) * 64 + rs] = v.x;
        Xt[(kq * 4 + 1) * 64 + rs] = v.y;
        Xt[(kq * 4 + 2) * 64 + rs] = v.z;
        Xt[(kq * 4 + 3) * 64 + rs] = v.w;
    }

    const int tx = t & 15;            // col group: cols tx*4..+3
    const int ty = t >> 4;            // row group: rows ty*4..+3
    const float4 asv = ((const float4*)a_src)[tx];
    const float4 adv = ((const float4*)a_dst)[tx];
    __syncthreads();

    float4 acc0 = make_float4(0.f,0.f,0.f,0.f);
    float4 acc1 = make_float4(0.f,0.f,0.f,0.f);
    float4 acc2 = make_float4(0.f,0.f,0.f,0.f);
    float4 acc3 = make_float4(0.f,0.f,0.f,0.f);

    #pragma unroll 8
    for (int k = 0; k < 64; ++k) {
        int swz = (k >> 2) & 3;
        const float4 xr = *(const float4*)&Xt[k * 64 + ((ty ^ swz) << 2)];
        const float4 wv = Wl[k * 16 + tx];
        acc0.x += xr.x * wv.x; acc0.y += xr.x * wv.y;
        acc0.z += xr.x * wv.z; acc0.w += xr.x * wv.w;
        acc1.x += xr.y * wv.x; acc1.y += xr.y * wv.y;
        acc1.z += xr.y * wv.z; acc1.w += xr.y * wv.w;
        acc2.x += xr.z * wv.x; acc2.y += xr.z * wv.y;
        acc2.z += xr.z * wv.z; acc2.w += xr.z * wv.w;
        acc3.x += xr.w * wv.x; acc3.y += xr.w * wv.y;
        acc3.z += xr.w * wv.z; acc3.w += xr.w * wv.w;
    }

    float4 accs[4] = {acc0, acc1, acc2, acc3};
    #pragma unroll
    for (int r = 0; r < 4; ++r) {
        int grow = n0 + ty * 4 + r;
        float4 a = accs[r];
        if (grow < N) ((float4*)h)[(size_t)grow * 16 + tx] = a;
        float ps = a.x * asv.x + a.y * asv.y + a.z * asv.z + a.w * asv.w;
        float pd = a.x * adv.x + a.y * adv.y + a.z * adv.z + a.w * adv.w;
        #pragma unroll
        for (int o = 8; o > 0; o >>= 1) {
            ps += __shfl_xor(ps, o);
            pd += __shfl_xor(pd, o);
        }
        if (tx == 0 && grow < N) { es[grow] = ps; ed[grow] = pd; }
    }
}

__global__ void __launch_bounds__(256) gemm2_kernel(
    const float* __restrict__ hid, const float* __restrict__ W,
    const float* __restrict__ a_src, const float* __restrict__ a_dst,
    float* __restrict__ h2, float* __restrict__ es, float* __restrict__ ed, int N)
{
    __shared__ float Wl[64 * 8];
    __shared__ float asl[8], adl[8];
    for (int i = threadIdx.x; i < 64 * 8; i += 256) Wl[i] = W[i];
    if (threadIdx.x < 8) {
        asl[threadIdx.x] = a_src[threadIdx.x];
        adl[threadIdx.x] = a_dst[threadIdx.x];
    }
    __syncthreads();
    const int lane = threadIdx.x & 63;
    const int wid  = threadIdx.x >> 6;
    const int r = lane >> 3, c = lane & 7;
    for (int base = (blockIdx.x * 4 + wid) * 8; base < N; base += gridDim.x * 32) {
        int row = base + r;
        float acc = 0.f;
        if (row < N) {
            #pragma unroll 8
            for (int k = 0; k < 64; ++k)
                acc += hid[(size_t)row * 64 + k] * Wl[k * 8 + c];
            h2[(size_t)row * 8 + c] = acc;
        }
        float ps = acc * asl[c];
        float pd = acc * adl[c];
        #pragma unroll
        for (int off = 4; off > 0; off >>= 1) {
            ps += __shfl_xor(ps, off);
            pd += __shfl_xor(pd, off);
        }
        if (row < N && c == 0) { es[row] = ps; ed[row] = pd; }
    }
}

// ---------------- attention coefficients ----------------
__global__ void __launch_bounds__(256) attn_kernel(
    const int* __restrict__ off, const int* __restrict__ csr_src,
    const float* __restrict__ csr_ev, const float* __restrict__ es,
    const float* __restrict__ ed, float* __restrict__ w, int N)
{
    const int wid = threadIdx.x >> 6, lane = threadIdx.x & 63;
    int n = blockIdx.x * 4 + wid;
    if (n >= N) return;
    const int beg = off[n], end = off[n + 1];
    const float edn = ed[n];

    float mx = -INFINITY;
    for (int i = beg + lane; i < end; i += 64) {
        float z = es[csr_src[i]] + edn;
        float l = z > 0.f ? z : 0.2f * z;
        w[i] = l;
        mx = fmaxf(mx, l);
    }
    #pragma unroll
    for (int o = 32; o > 0; o >>= 1) mx = fmaxf(mx, __shfl_xor(mx, o));

    float den = 0.f;
    for (int i = beg + lane; i < end; i += 64) {
        float exv = expf(w[i] - mx);
        w[i] = exv;
        den += exv;
    }
    #pragma unroll
    for (int o = 32; o > 0; o >>= 1) den += __shfl_xor(den, o);

    float inv = 1.f / (den + 1e-16f);
    for (int i = beg + lane; i < end; i += 64)
        w[i] = w[i] * inv * csr_ev[i];
}

// ---------------- aggregation ----------------

__global__ void __launch_bounds__(256) agg64_kernel(
    const int* __restrict__ off, const int* __restrict__ csr_src,
    const float* __restrict__ w, const float* __restrict__ h,
    const float* __restrict__ b, float* __restrict__ outAgg, int N)
{
    const int wid = threadIdx.x >> 6, lane = threadIdx.x & 63;
    int n = blockIdx.x * 4 + wid;
    if (n >= N) return;
    const int beg = off[n], end = off[n + 1];
    const int g  = lane >> 4;
    const int c4 = lane & 15;

    float4 acc = make_float4(0.f, 0.f, 0.f, 0.f);
    for (int i = beg; i < end; i += 4) {
        int e = i + g;
        if (e < end) {
            int s = csr_src[e];
            float wt = w[e];
            const float4 hv = *(const float4*)&h[(size_t)s * 64 + (c4 << 2)];
            acc.x += wt * hv.x;
            acc.y += wt * hv.y;
            acc.z += wt * hv.z;
            acc.w += wt * hv.w;
        }
    }
    acc.x += __shfl_xor(acc.x, 16); acc.y += __shfl_xor(acc.y, 16);
    acc.z += __shfl_xor(acc.z, 16); acc.w += __shfl_xor(acc.w, 16);
    acc.x += __shfl_xor(acc.x, 32); acc.y += __shfl_xor(acc.y, 32);
    acc.z += __shfl_xor(acc.z, 32); acc.w += __shfl_xor(acc.w, 32);

    if (g == 0) {
        const float4 bb = *(const float4*)&b[c4 << 2];
        float4 v;
        v.x = fmaxf(acc.x + bb.x, 0.f);
        v.y = fmaxf(acc.y + bb.y, 0.f);
        v.z = fmaxf(acc.z + bb.z, 0.f);
        v.w = fmaxf(acc.w + bb.w, 0.f);
        *(float4*)&outAgg[(size_t)n * 64 + (c4 << 2)] = v;
    }
}

__global__ void __launch_bounds__(256) agg8_lsm_kernel(
    const int* __restrict__ off, const int* __restrict__ csr_src,
    const float* __restrict__ w, const float* __restrict__ h2,
    const float* __restrict__ b, float* __restrict__ out, int N)
{
    const int wid = threadIdx.x >> 6, lane = threadIdx.x & 63;
    int n = blockIdx.x * 4 + wid;
    if (n >= N) return;
    const int beg = off[n], end = off[n + 1];
    const int g = lane >> 3;
    const int c = lane & 7;

    float acc = 0.f;
    for (int i = beg; i < end; i += 8) {
        int e = i + g;
        if (e < end) {
            int s = csr_src[e];
            acc += w[e] * h2[(size_t)s * 8 + c];
        }
    }
    acc += __shfl_xor(acc, 8);
    acc += __shfl_xor(acc, 16);
    acc += __shfl_xor(acc, 32);

    float v = acc + b[c];
    float vm = v;
    vm = fmaxf(vm, __shfl_xor(vm, 1));
    vm = fmaxf(vm, __shfl_xor(vm, 2));
    vm = fmaxf(vm, __shfl_xor(vm, 4));
    float s = expf(v - vm);
    s += __shfl_xor(s, 1);
    s += __shfl_xor(s, 2);
    s += __shfl_xor(s, 4);
    float lse = vm + logf(s);
    if (lane < 8) out[(size_t)n * 8 + lane] = v - lse;
}

// ---------------------------------------------------------------------------

extern "C" void kernel_launch(void* const* d_in, const int* in_sizes, int n_in,
                              void* d_out, int out_size, void* d_ws, size_t ws_size,
                              hipStream_t stream)
{
    const float* x   = (const float*)d_in[0];
    const int*   ei  = (const int*)d_in[1];
    const float* ev  = (const float*)d_in[2];
    const float* W1  = (const float*)d_in[3];
    const float* a1s = (const float*)d_in[4];
    const float* a1d = (const float*)d_in[5];
    const float* b1  = (const float*)d_in[6];
    const float* W2  = (const float*)d_in[7];
    const float* a2s = (const float*)d_in[8];
    const float* a2d = (const float*)d_in[9];
    const float* b2  = (const float*)d_in[10];
    float* out = (float*)d_out;

    const int N = in_sizes[0] / 64;
    const int E = in_sizes[2];
    const int* srcp = ei;
    const int* dstp = ei + E;
    const int nchunks = (E + CHUNK - 1) / CHUNK;
    const int nbuck = (N + 255) / 256;

    // Workspace (8B-aligned first):
    //  ped E ull | hist 256 | boff 257 | cursor 256 | off N+1 |
    //  csrs E | csrv E | wbuf E | es1 N | ed1 N | h1 64N | agg1 64N
    unsigned long long* ped = (unsigned long long*)d_ws;
    int*   hist   = (int*)(ped + E);
    int*   boff   = hist + 256;
    int*   cursor = boff + 257;
    int*   off    = cursor + 256;          // N+1
    int*   csrs   = off + N + 1;
    float* csrv   = (float*)(csrs + E);
    float* wbuf   = csrv + E;
    float* es1    = wbuf + E;
    float* ed1    = es1 + N;
    float* h1     = ed1 + N;
    float* agg1   = h1 + (size_t)N * 64;
    float* h2     = h1;                     // h1 dead after agg64
    float* es2    = h1 + (size_t)N * 8;
    float* ed2    = es2 + N;

    hipMemsetAsync(hist, 0, 256 * sizeof(int), stream);

    // CSR build (radix partition)
    hist_kernel<<<nchunks, 256, 0, stream>>>(dstp, hist, E);
    bscan_kernel<<<1, 256, 0, stream>>>(hist, boff, cursor);
    part_kernel<<<nchunks, 256, 0, stream>>>(srcp, dstp, ev, cursor, ped, E);
    csr_kernel<<<nbuck, 256, 0, stream>>>(ped, boff, off, csrs, csrv, N, E);

    // Layer 1
    gemm1_kernel<<<(N + 63) / 64, 256, 0, stream>>>(x, W1, a1s, a1d, h1, es1, ed1, N);
    attn_kernel<<<(N + 3) / 4, 256, 0, stream>>>(off, csrs, csrv, es1, ed1, wbuf, N);
    agg64_kernel<<<(N + 3) / 4, 256, 0, stream>>>(off, csrs, wbuf, h1, b1, agg1, N);

    // Layer 2
    gemm2_kernel<<<1024, 256, 0, stream>>>(agg1, W2, a2s, a2d, h2, es2, ed2, N);
    attn_kernel<<<(N + 3) / 4, 256, 0, stream>>>(off, csrs, csrv, es2, ed2, wbuf, N);
    agg8_lsm_kernel<<<(N + 3) / 4, 256, 0, stream>>>(off, csrs, wbuf, h2, b2, out, N);
}